// Round 13
// baseline (122.699 us; speedup 1.0000x reference)
//
#include <hip/hip_runtime.h>
#include <hip/hip_bf16.h>

// all I/O is float32 (reference is pure jnp.float32)
// R13 = R12 bit-identical, with k_conv_mfma launched 3x (idempotent) as a pure
// instrumentation round: delta(dur_us) / 2 = conv kernel time at warm cache state.

typedef __attribute__((ext_vector_type(8))) short bf16x8;
typedef __attribute__((ext_vector_type(4))) float f32x4;

#define AS1 __attribute__((address_space(1)))
#define AS3 __attribute__((address_space(3)))

// ---- ws layout (f32 element offsets) ----
#define O_WPK   0          // Wpack [tap9][cb16][co64][cin32] bf16 (big convs)
#define O_W51P  147456     // [tap9][co32][ci32] bf16
#define O_W52P  152064
#define O_BNA   156672     // [conv{5a,5c,51,52}][{A,B}][32]
#define O_W8    156928     // w8[2][32], b8 at +64
#define O_PQW   157000     // [4][32], bias at +128
#define O_PKW   157132
#define O_PVW   157264     // [32][32], bias at +1024
#define O_GAM   158320     // p_gamma, c_gamma
#define O_Q     158400     // [b4][cr4][4096] f32
#define O_K     223936     // [b4][cr4][4096] f32
#define O_ENE   453312     // [4][32][32]
#define O_F1T   985792     // [b][4096][32] f32 NHWC
#define O_F2T   1510080    // [b][4096][32] f32 NHWC
#define O_V     2034368    // [b][32][4096] bf16
// conv-phase overlay (Xt dead after k_conv_mfma). XT is GRANULE-SWIZZLED:
// logical granule (px, q) of a row lives at byte px*64 + (q ^ ((px>>1)&3))*16.
#define O_XT    461504     // Xt[b4][cb16][66][66][32] bf16 (ends 4922048)
#define O_CP    4922048    // conv partials f32 [ks4][b4][4096pix][64co] (ends 9116352)
// PAM-phase overlays (CP dead after k_feat):
#define O_PO    4922048    // PAM partial O [ms4][b4][n4096][c32] f32 (= old CP)
#define O_PS    3116224    // PAM partial S [ms4][b4][n4096] f32 (inside dead XT)
#define O_PE2   9437184    // CAM energy partials [b4][ch128][32][32] f32 (ends 9961472)
// SAT/SCT OUT of the XT overlay: halo zeroing happens in prep.
#define O_SAT   9961472    // [b][66][66][32] bf16 padded (ends 10240256)
#define O_SCT   10240256   // (ends 10519040; ws ~268MB)

__device__ __forceinline__ unsigned short f2b(float f){
  __hip_bfloat16 h = __float2bfloat16(f);
  return *(unsigned short*)&h;
}

// ---------------- fused: NHWC transform + prep (wpack/misc/XT border/SA-SC halo) ----------------
__global__ __launch_bounds__(256) void k_prep_nhwc(
  const float* __restrict__ x,
  const float* w5a, const float* w5c,
  const float* w51, const float* w52,
  const float* s0,const float* b0,const float* m0,const float* v0,
  const float* s1,const float* b1,const float* m1,const float* v1,
  const float* s2,const float* b2,const float* m2,const float* v2,
  const float* s3,const float* b3,const float* m3,const float* v3,
  const float* w8,const float* b8,
  const float* pqw,const float* pqb,const float* pkw,const float* pkb,
  const float* pvw,const float* pvb,const float* pg,const float* cg,
  float* ws)
{
  int bx = blockIdx.x;
  int tid = threadIdx.x;
  __shared__ unsigned short t16[64][65];
  if (bx < 2048){
    // ---- NHWC+pad bf16 transform -> swizzled Xt[b][cb16][66][66][32]
    int y = bx & 63, ct = (bx >> 6) & 7, b = bx >> 9;
    int r0 = tid >> 4, c0 = (tid & 15) * 4;
    const float* xb = x + ((size_t)(b*512 + ct*64))*4096 + y*64;
    #pragma unroll
    for (int i = 0; i < 4; ++i){
      int row = r0 + i*16;
      float4 v = *(const float4*)(xb + (size_t)row*4096 + c0);
      t16[row][c0+0] = f2b(v.x);
      t16[row][c0+1] = f2b(v.y);
      t16[row][c0+2] = f2b(v.z);
      t16[row][c0+3] = f2b(v.w);
    }
    __syncthreads();
    int pixl = tid >> 2, q = tid & 3;
    unsigned short vs[16];
    #pragma unroll
    for (int j = 0; j < 16; ++j) vs[j] = t16[q*16 + j][pixl];
    unsigned u[8];
    #pragma unroll
    for (int j = 0; j < 8; ++j) u[j] = (unsigned)vs[2*j] | ((unsigned)vs[2*j+1] << 16);
    unsigned short* xt = (unsigned short*)(ws + O_XT);
    int cbl = ct*2 + (q>>1);
    int pxe = pixl + 1;
    int sw = (pxe >> 1) & 3;                 // granule swizzle for this pixel
    int g0 = (2*(q&1)) ^ sw;                 // logical granules 2(q&1), 2(q&1)+1
    int g1 = g0 ^ 1;
    size_t base = (((size_t)(b*16 + cbl)*66 + (y+1))*66 + pxe)*32;
    *(uint4*)(xt + base + g0*8) = make_uint4(u[0],u[1],u[2],u[3]);
    *(uint4*)(xt + base + g1*8) = make_uint4(u[4],u[5],u[6],u[7]);
    return;
  }
  int pbx = bx - 2048;
  if (pbx < 1152){
    int id = pbx*256 + tid;   // 294912
    int tap = id >> 15;
    int r = id & 32767;
    int cb = r >> 11;
    int r2 = r & 2047;
    int co = r2 >> 5, ci = r2 & 31;
    int cin = cb*32 + ci;
    float v = (co < 32) ? w5a[co*4608 + cin*9 + tap] : w5c[(co-32)*4608 + cin*9 + tap];
    ((unsigned short*)ws)[id] = f2b(v);
    return;
  }
  if (pbx < 1231){
    int id = (pbx-1152)*256 + tid;
    if (id >= 20076) return;
    if (id < 9216){ int tap=id>>10, co=(id>>5)&31, ci=id&31;
      ((unsigned short*)(ws + O_W51P))[id] = f2b(w51[co*288 + ci*9 + tap]); return; }
    id -= 9216;
    if (id < 9216){ int tap=id>>10, co=(id>>5)&31, ci=id&31;
      ((unsigned short*)(ws + O_W52P))[id] = f2b(w52[co*288 + ci*9 + tap]); return; }
    id -= 9216;
    if (id < 256){
      int conv = id>>6, ab = (id>>5)&1, c = id&31;
      const float *S,*Bb,*M,*V;
      if (conv==0){S=s0;Bb=b0;M=m0;V=v0;} else if (conv==1){S=s1;Bb=b1;M=m1;V=v1;}
      else if (conv==2){S=s2;Bb=b2;M=m2;V=v2;} else {S=s3;Bb=b3;M=m3;V=v3;}
      float A = S[c] * rsqrtf(V[c] + 1e-5f);
      ws[O_BNA + conv*64 + ab*32 + c] = ab ? (Bb[c] - M[c]*A) : A;
      return; }
    id -= 256;
    if (id < 64){ ws[O_W8+id] = w8[id]; return; } id -= 64;
    if (id < 2){ ws[O_W8+64+id] = b8[id]; return; } id -= 2;
    if (id < 128){ ws[O_PQW+id] = pqw[id]; return; } id -= 128;
    if (id < 4){ ws[O_PQW+128+id] = pqb[id]; return; } id -= 4;
    if (id < 128){ ws[O_PKW+id] = pkw[id]; return; } id -= 128;
    if (id < 4){ ws[O_PKW+128+id] = pkb[id]; return; } id -= 4;
    if (id < 1024){ ws[O_PVW+id] = pvw[id]; return; } id -= 1024;
    if (id < 32){ ws[O_PVW+1024+id] = pvb[id]; return; } id -= 32;
    ws[O_GAM+id] = id ? cg[0] : pg[0];
    return;
  }
  if (pbx < 1491){
    // ---- zero Xt borders: whole 64B pixels zeroed -> granule swizzle irrelevant
    int i = (pbx-1231)*256 + tid;   // 66560 uint4
    if (i >= 66560) return;
    int part = i & 3; int j = i >> 2;
    int rp = j % 260; int bc = j / 260;
    int py, px;
    if (rp < 66){ py = 0; px = rp; }
    else if (rp < 132){ py = 65; px = rp - 66; }
    else if (rp < 196){ py = rp - 131; px = 0; }
    else { py = rp - 195; px = 65; }
    size_t off = (((size_t)bc*66 + py)*66 + px)*32 + part*8;
    *(uint4*)((unsigned short*)(ws + O_XT) + off) = make_uint4(0,0,0,0);
    return;
  }
  {
    // ---- zero SA_t / SC_t borders (SAT/SCT do not alias XT — safe here)
    int i = (pbx-1491)*256 + tid;   // 8320 uint4
    if (i >= 8320) return;
    int part = i & 3; int j = i >> 2;
    int arr = j / 1040; int rem = j - arr*1040;
    int b = rem / 260; int rp = rem % 260;
    int py, px;
    if (rp < 66){ py = 0; px = rp; }
    else if (rp < 132){ py = 65; px = rp - 66; }
    else if (rp < 196){ py = rp - 131; px = 0; }
    else { py = rp - 195; px = 65; }
    size_t off = (((size_t)(b*66) + py)*66 + px)*32 + part*8;
    unsigned short* base = (unsigned short*)(ws + (arr ? O_SCT : O_SAT));
    *(uint4*)(base + off) = make_uint4(0,0,0,0);
  }
}

// ---------------- big convs as implicit GEMM via MFMA (glds dbuf + weight reg-prefetch) ----------------
__global__ __launch_bounds__(256, 4) void k_conv_mfma(float* __restrict__ ws){
  int bx = blockIdx.x;          // 1024 flat
  int xcd = bx & 7, kk2 = bx >> 3;
  int pairIdx = ((kk2 >> 6) << 3) + xcd;   // 0..15
  int b = pairIdx >> 2, ks = pairIdx & 3;
  int y = kk2 & 63;
  __shared__ __align__(16) unsigned short Bs[2][6336];   // [buf][(dy*66+px)*32 + swz-granule]
  int tid = threadIdx.x;
  int w = tid >> 6, l = tid & 63;
  int bl = l & 15, qh = l >> 4;
  f32x4 zero = {0.f,0.f,0.f,0.f};
  f32x4 acc[4] = {zero, zero, zero, zero};
  const unsigned short* wp = (const unsigned short*)ws;
  const unsigned short* xt = (const unsigned short*)(ws + O_XT);
  int arow = w*16 + bl;
  int kq = qh*8;
  // swizzled read offsets: (px)*32 + (qh ^ ((px>>1)&3))*8 for px = bl+dx
  int qx0 = ((qh ^ ((bl>>1)&3)) << 3) + bl*32;
  int qx1 = ((qh ^ (((bl+1)>>1)&3)) << 3) + (bl+1)*32;
  int qx2 = ((qh ^ (((bl+2)>>1)&3)) << 3) + (bl+2)*32;
  bf16x8 afA[9], afB[9];

#define CF_STAGE(BUF, CB) { \
    const unsigned short* slab = xt + (size_t)((b*16 + (CB))*66 + y)*2112; \
    _Pragma("unroll") \
    for (int cc = 0; cc < 3; ++cc){ \
      int kk = w*3 + cc; \
      __builtin_amdgcn_global_load_lds((const AS1 unsigned int*)(slab + kk*512 + l*8), \
                                       (AS3 unsigned int*)(&Bs[BUF][kk*512]), 16, 0, 0); \
    } \
    if (w == 3 && l < 24) \
      __builtin_amdgcn_global_load_lds((const AS1 unsigned int*)(slab + 6144 + l*8), \
                                       (AS3 unsigned int*)(&Bs[BUF][6144]), 16, 0, 0); \
  }

#define CF_LOAD_AF(DST, CB) { \
    _Pragma("unroll") \
    for (int t = 0; t < 9; ++t) \
      DST[t] = *(const bf16x8*)(wp + (size_t)(t*16 + (CB))*2048 + arow*32 + kq); \
  }

#define CF_COMPUTE(BUF, AF) { \
    _Pragma("unroll") \
    for (int tap = 0; tap < 9; ++tap){ \
      int dy = tap/3, dx = tap - dy*3; \
      int qx = (dx==0) ? qx0 : (dx==1) ? qx1 : qx2; \
      _Pragma("unroll") \
      for (int pt = 0; pt < 4; ++pt){ \
        bf16x8 bv = *(const bf16x8*)&Bs[BUF][dy*2112 + pt*512 + qx]; \
        acc[pt] = __builtin_amdgcn_mfma_f32_16x16x32_bf16(AF[tap], bv, acc[pt], 0, 0, 0); \
      } \
    } }

  int cb0 = ks*4;
  CF_STAGE(0, cb0)
  CF_LOAD_AF(afA, cb0)
  __syncthreads();
  CF_STAGE(1, cb0+1)
  CF_LOAD_AF(afB, cb0+1)
  CF_COMPUTE(0, afA)
  __syncthreads();
  CF_STAGE(0, cb0+2)
  CF_LOAD_AF(afA, cb0+2)
  CF_COMPUTE(1, afB)
  __syncthreads();
  CF_STAGE(1, cb0+3)
  CF_LOAD_AF(afB, cb0+3)
  CF_COMPUTE(0, afA)
  __syncthreads();
  CF_COMPUTE(1, afB)
#undef CF_STAGE
#undef CF_LOAD_AF
#undef CF_COMPUTE

  float* cp = ws + O_CP + ((size_t)(ks*4 + b))*262144;
  int co0 = w*16 + qh*4;
  #pragma unroll
  for (int pt = 0; pt < 4; ++pt){
    int pix = y*64 + pt*16 + bl;
    *(f32x4*)&cp[(size_t)pix*64 + co0] = acc[pt];
  }
}

// ---------------- fused: CP reduce + BN/ReLU -> F1T/F2T (+LDS) + qkv + CAM partials ----------------
__global__ __launch_bounds__(256) void k_feat(float* __restrict__ ws){
  int bx = blockIdx.x;   // 512
  int tid = threadIdx.x;
  __shared__ float Fl[32][68];               // [pix][co64 +pad]
  __shared__ float wqs[4][32], wks[4][32], wvs[32][32];
  int b = bx >> 7, chunk = bx & 127;         // 128 chunks of 32 pix
  for (int i = tid; i < 1280; i += 256){
    if (i < 128)      ((float*)wqs)[i]     = ws[O_PQW + i];
    else if (i < 256) ((float*)wks)[i-128] = ws[O_PKW + (i-128)];
    else              ((float*)wvs)[i-256] = ws[O_PVW + (i-256)];
  }
  int pix = tid >> 3, cg = tid & 7;          // 8 co per thread
  int pixg = (chunk << 5) + pix;
  const float* cpb = ws + O_CP + (size_t)b*262144 + (size_t)pixg*64 + cg*8;
  f32x4 sa_ = *(const f32x4*)(cpb);
  f32x4 sb_ = *(const f32x4*)(cpb + 4);
  {
    f32x4 t0 = *(const f32x4*)(cpb + 1048576);
    f32x4 t1 = *(const f32x4*)(cpb + 1048576 + 4);
    f32x4 t2 = *(const f32x4*)(cpb + 2097152);
    f32x4 t3 = *(const f32x4*)(cpb + 2097152 + 4);
    f32x4 t4 = *(const f32x4*)(cpb + 3145728);
    f32x4 t5 = *(const f32x4*)(cpb + 3145728 + 4);
    sa_ = (sa_ + t0) + (t2 + t4);
    sb_ = (sb_ + t1) + (t3 + t5);
  }
  int co0 = cg*8;
  int conv = co0 >> 5, cc0 = co0 & 31;       // 8-group never straddles conv boundary
  float v8[8];
  #pragma unroll
  for (int j = 0; j < 8; ++j){
    int c = cc0 + j;
    float A = ws[O_BNA + conv*64 + c], Bb = ws[O_BNA + conv*64 + 32 + c];
    float s = (j < 4) ? sa_[j] : sb_[j-4];
    v8[j] = fmaxf(A*s + Bb, 0.f);
  }
  float* fdst = ws + (conv == 0 ? O_F1T : O_F2T) + ((size_t)(b*4096 + pixg))*32 + cc0;
  *(f32x4*)(fdst)     = (f32x4){v8[0],v8[1],v8[2],v8[3]};
  *(f32x4*)(fdst + 4) = (f32x4){v8[4],v8[5],v8[6],v8[7]};
  *(f32x4*)&Fl[pix][co0]     = (f32x4){v8[0],v8[1],v8[2],v8[3]};
  *(f32x4*)&Fl[pix][co0 + 4] = (f32x4){v8[4],v8[5],v8[6],v8[7]};
  __syncthreads();
  // ---- qkv phase (threads 0..127): part, pixel
  if (tid < 128){
    int part = tid >> 5, pixl = tid & 31;
    int n = (chunk << 5) + pixl;
    float fv[32];
    #pragma unroll
    for (int c = 0; c < 32; ++c) fv[c] = Fl[pixl][c];
    float q = ws[O_PQW+128+part], k = ws[O_PKW+128+part];
    #pragma unroll
    for (int c = 0; c < 32; ++c){ q += wqs[part][c]*fv[c]; k += wks[part][c]*fv[c]; }
    ws[O_Q + (((b<<2)+part)<<12) + n] = q;
    ws[O_K + (((b<<2)+part)<<12) + n] = k;
    unsigned short* vbp = (unsigned short*)(ws + O_V);
    #pragma unroll
    for (int j2 = 0; j2 < 8; ++j2){
      int c2 = part*8 + j2;
      float v = ws[O_PVW+1024+c2];
      #pragma unroll
      for (int c = 0; c < 32; ++c) v += wvs[c2][c]*fv[c];
      vbp[(((b<<5)+c2)<<12) + n] = f2b(v);
    }
  }
  // ---- CAM energy partial (all 256 threads), F2 = Fl[:,32..63]
  {
    int ce = tid >> 3, d0 = (tid & 7) * 4;
    float a0=0.f, a1=0.f, a2=0.f, a3=0.f;
    #pragma unroll 8
    for (int n = 0; n < 32; ++n){
      float fc = Fl[n][32 + ce];
      float f0 = Fl[n][32 + d0], f1 = Fl[n][32 + d0 + 1];
      float f2 = Fl[n][32 + d0 + 2], f3 = Fl[n][32 + d0 + 3];
      a0 = fmaf(fc, f0, a0); a1 = fmaf(fc, f1, a1);
      a2 = fmaf(fc, f2, a2); a3 = fmaf(fc, f3, a3);
    }
    float* pe = ws + O_PE2 + ((size_t)(b*128 + chunk))*1024 + ce*32 + d0;
    *(f32x4*)pe = (f32x4){a0, a1, a2, a3};
  }
}

// ---------------- PAM flash, 32-n tiles, m-split x4, V direct-to-register ----------------
__global__ __launch_bounds__(256, 6) void k_pam_flash(float* __restrict__ ws){
  int bx = blockIdx.x;
  int xcd = bx & 7, kf = bx >> 3;       // kf 0..255
  int pair = ((kf >> 7) << 3) + xcd;    // 0..15
  int b  = pair >> 2;
  int ms = pair & 3;
  int nt = kf & 127;                    // 0..127 n-tile of 32
  __shared__ float Ks[2][4][4][32];    // [buf][wave][cr][m32]  4 KB
  __shared__ float Ss[4][32];
  __shared__ float Os[4][32][36];      // 18 KB
  int tid = threadIdx.x;
  int w = tid >> 6, l = tid & 63;
  int nn = l & 15, g = l >> 4;
  int n0 = (nt<<5) + nn;
  const float LOG2E = 1.44269504f;
  const float BIAS  = -28.8539008f;   // -20*log2(e); fixed shift, energies O(+-35)
  float q0[4], q1[4];
  #pragma unroll
  for (int cr=0;cr<4;++cr){
    q0[cr] = ws[O_Q + (((b<<2)+cr)<<12) + n0] * LOG2E;
    q1[cr] = ws[O_Q + (((b<<2)+cr)<<12) + n0 + 16] * LOG2E;
  }
  int e0i = l*2, cr_s = e0i >> 5, mm_s = e0i & 31;
  int mbase = ms*1024 + w*256;        // wave owns m in [mbase, mbase+256), 8 chunks
  const float* ksrc = ws + O_K + (((b<<2)+cr_s)<<12) + mbase + mm_s;
  const unsigned short* vb = (const unsigned short*)(ws + O_V);
  int mo = g*8;
  const unsigned short* vp0 = vb + (((b<<5) + nn)<<12) + mbase + mo;
  const unsigned short* vp1 = vb + (((b<<5) + 16 + nn)<<12) + mbase + mo;
  f32x4 zero = {0.f,0.f,0.f,0.f};
  f32x4 acc00 = zero, acc01 = zero, acc10 = zero, acc11 = zero;
  float lsum0 = 0.f, lsum1 = 0.f;
  bf16x8 a0A = *(const bf16x8*)(vp0);
  bf16x8 a1A = *(const bf16x8*)(vp1);
  float2 kreg = *(const float2*)(ksrc);
  *(float2*)&Ks[0][w][cr_s][mm_s] = kreg;
  bf16x8 a0B, a1B;
  for (int ch = 0; ch < 8; ++ch){
    int buf = ch & 1;
    if (ch < 7){
      int mn = (ch+1)*32;
      a0B = *(const bf16x8*)(vp0 + mn);
      a1B = *(const bf16x8*)(vp1 + mn);
      kreg = *(const float2*)(ksrc + mn);
    }
    float e0[8], e1[8];
    {
      float4 ka, kb;
      ka = *(const float4*)&Ks[buf][w][0][mo];
      kb = *(const float4*)&Ks[buf][w][0][mo+4];
      e0[0]=fmaf(q0[0],ka.x,BIAS); e0[1]=fmaf(q0[0],ka.y,BIAS); e0[2]=fmaf(q0[0],ka.z,BIAS); e0[3]=fmaf(q0[0],ka.w,BIAS);
      e0[4]=fmaf(q0[0],kb.x,BIAS); e0[5]=fmaf(q0[0],kb.y,BIAS); e0[6]=fmaf(q0[0],kb.z,BIAS); e0[7]=fmaf(q0[0],kb.w,BIAS);
      e1[0]=fmaf(q1[0],ka.x,BIAS); e1[1]=fmaf(q1[0],ka.y,BIAS); e1[2]=fmaf(q1[0],ka.z,BIAS); e1[3]=fmaf(q1[0],ka.w,BIAS);
      e1[4]=fmaf(q1[0],kb.x,BIAS); e1[5]=fmaf(q1[0],kb.y,BIAS); e1[6]=fmaf(q1[0],kb.z,BIAS); e1[7]=fmaf(q1[0],kb.w,BIAS);
#define KACC(CR) \
      ka = *(const float4*)&Ks[buf][w][CR][mo]; \
      kb = *(const float4*)&Ks[buf][w][CR][mo+4]; \
      e0[0]=fmaf(q0[CR],ka.x,e0[0]); e0[1]=fmaf(q0[CR],ka.y,e0[1]); e0[2]=fmaf(q0[CR],ka.z,e0[2]); e0[3]=fmaf(q0[CR],ka.w,e0[3]); \
      e0[4]=fmaf(q0[CR],kb.x,e0[4]); e0[5]=fmaf(q0[CR],kb.y,e0[5]); e0[6]=fmaf(q0[CR],kb.z,e0[6]); e0[7]=fmaf(q0[CR],kb.w,e0[7]); \
      e1[0]=fmaf(q1[CR],ka.x,e1[0]); e1[1]=fmaf(q1[CR],ka.y,e1[1]); e1[2]=fmaf(q1[CR],ka.z,e1[2]); e1[3]=fmaf(q1[CR],ka.w,e1[3]); \
      e1[4]=fmaf(q1[CR],kb.x,e1[4]); e1[5]=fmaf(q1[CR],kb.y,e1[5]); e1[6]=fmaf(q1[CR],kb.z,e1[6]); e1[7]=fmaf(q1[CR],kb.w,e1[7]);
      KACC(1)
      KACC(2)
      KACC(3)
#undef KACC
    }
    union { bf16x8 v; unsigned short u[8]; } pb0, pb1;
    #pragma unroll
    for (int j=0;j<8;j++){ float p = __builtin_amdgcn_exp2f(e0[j]); lsum0 += p; pb0.u[j] = f2b(p); }
    #pragma unroll
    for (int j=0;j<8;j++){ float p = __builtin_amdgcn_exp2f(e1[j]); lsum1 += p; pb1.u[j] = f2b(p); }
    acc00 = __builtin_amdgcn_mfma_f32_16x16x32_bf16(a0A, pb0.v, acc00, 0, 0, 0);
    acc01 = __builtin_amdgcn_mfma_f32_16x16x32_bf16(a1A, pb0.v, acc01, 0, 0, 0);
    acc10 = __builtin_amdgcn_mfma_f32_16x16x32_bf16(a0A, pb1.v, acc10, 0, 0, 0);
    acc11 = __builtin_amdgcn_mfma_f32_16x16x32_bf16(a1A, pb1.v, acc11, 0, 0, 0);
    if (ch < 7){
      int nb = buf ^ 1;
      *(float2*)&Ks[nb][w][cr_s][mm_s] = kreg;
      a0A = a0B; a1A = a1B;
    }
  }
  lsum0 += __shfl_xor(lsum0, 16); lsum0 += __shfl_xor(lsum0, 32);
  lsum1 += __shfl_xor(lsum1, 16); lsum1 += __shfl_xor(lsum1, 32);
  if (l < 16){ Ss[w][l] = lsum0; Ss[w][16+l] = lsum1; }
  #pragma unroll
  for (int r=0;r<4;r++){
    Os[w][nn][g*4 + r]         = acc00[r];
    Os[w][nn][16 + g*4 + r]    = acc01[r];
    Os[w][16+nn][g*4 + r]      = acc10[r];
    Os[w][16+nn][16 + g*4 + r] = acc11[r];
  }
  __syncthreads();
  float* PO = ws + O_PO + (size_t)(ms*4+b)*131072 + nt*1024;
  for (int i = tid; i < 1024; i += 256){
    int nn2 = i >> 5, c = i & 31;
    PO[i] = Os[0][nn2][c] + Os[1][nn2][c] + Os[2][nn2][c] + Os[3][nn2][c];
  }
  if (tid < 32)
    ws[O_PS + (ms*4+b)*4096 + (nt<<5) + tid] = Ss[0][tid]+Ss[1][tid]+Ss[2][tid]+Ss[3][tid];
}

// ---------------- fused: PAM finalize (vectorized, 4 ch/thread) + CAM energy reduce ----------------
__global__ __launch_bounds__(256) void k_finred(float* __restrict__ ws){
  int bx = blockIdx.x;
  int tid = threadIdx.x;
  if (bx < 512){
    int id = bx*256 + tid;   // 131072 = (b, n, c-quad)
    int cq = (id & 7) * 4;
    int n  = (id >> 3) & 4095;
    int b  = id >> 15;
    size_t pbase = (size_t)(b*4096 + n)*32 + cq;
    int sbase = b*4096 + n;
    f32x4 O = *(const f32x4*)(ws + O_PO + pbase);
    O = O + *(const f32x4*)(ws + O_PO + 524288 + pbase);
    O = O + *(const f32x4*)(ws + O_PO + 1048576 + pbase);
    O = O + *(const f32x4*)(ws + O_PO + 1572864 + pbase);
    float S = ws[O_PS + sbase] + ws[O_PS + 16384 + sbase]
            + ws[O_PS + 32768 + sbase] + ws[O_PS + 49152 + sbase];
    float gam = ws[O_GAM];
    f32x4 f1 = *(const f32x4*)(ws + O_F1T + (size_t)id*4);
    unsigned short h[4];
    #pragma unroll
    for (int j = 0; j < 4; ++j) h[j] = f2b(gam*(O[j]/S) + f1[j]);
    int y = n >> 6, xx = n & 63;
    unsigned short* sat = (unsigned short*)(ws + O_SAT);
    uint2 u; u.x = (unsigned)h[0] | ((unsigned)h[1] << 16);
             u.y = (unsigned)h[2] | ((unsigned)h[3] << 16);
    *(uint2*)&sat[(((size_t)((b*66 + y+1)*66 + xx+1))<<5) + cq] = u;
    return;
  }
  {
    int id = (bx-512)*256 + tid;   // 4096 = b*1024 + i
    int b = id >> 10, i = id & 1023;
    const float* pe = ws + O_PE2 + ((size_t)b)*131072 + i;
    float s = 0.f;
    #pragma unroll 8
    for (int chk = 0; chk < 128; ++chk) s += pe[chk*1024];
    ws[O_ENE + id] = s;
  }
}

// ---------------- CAM att (in-block) + out -> SC_t ----------------
__global__ __launch_bounds__(256) void k_cam_out(float* __restrict__ ws){
  int blk = blockIdx.x;            // 128
  int b = blk >> 5;
  int chunk = blk & 31;
  int tid = threadIdx.x;
  int half = tid >> 7;             // 0/1
  int nl = tid & 127;
  int n = (chunk << 7) + nl;
  __shared__ float att[32][33];
  if (tid < 32){
    int c = tid;
    const float* e = ws + O_ENE + (b<<10) + (c<<5);
    float M = -1e30f, mn = 1e30f;
    #pragma unroll
    for (int d=0;d<32;d++){ M = fmaxf(M, e[d]); mn = fminf(mn, e[d]); }
    float mx2 = M - mn;
    float s = 0.f, ex[32];
    #pragma unroll
    for (int d=0;d<32;d++){ ex[d] = __expf((M - e[d]) - mx2); s += ex[d]; }
    float inv = 1.f/s;
    #pragma unroll
    for (int d=0;d<32;d++) att[c][d] = ex[d]*inv;
  }
  __syncthreads();
  const float* fp = ws + O_F2T + (((size_t)b<<12) + n)*32;
  float fv[32];
  #pragma unroll
  for (int j=0;j<8;j++){
    float4 v = *(const float4*)(fp + j*4);
    fv[j*4]=v.x; fv[j*4+1]=v.y; fv[j*4+2]=v.z; fv[j*4+3]=v.w;
  }
  float g = ws[O_GAM+1];
  int c0 = half*16;
  unsigned u[8];
  #pragma unroll
  for (int cp=0; cp<8; ++cp){
    int ca = c0 + 2*cp, cb = ca + 1;
    float o0 = 0.f, o1 = 0.f;
    #pragma unroll
    for (int d=0;d<32;d++){ o0 += att[ca][d]*fv[d]; o1 += att[cb][d]*fv[d]; }
    float r0 = g*o0 + fv[ca], r1 = g*o1 + fv[cb];
    u[cp] = (unsigned)f2b(r0) | ((unsigned)f2b(r1) << 16);
  }
  int y = n >> 6, xcol = n & 63;
  unsigned short* sct = (unsigned short*)(ws + O_SCT);
  size_t base = ((size_t)((b*66 + y+1)*66 + xcol+1))*32 + c0;
  *(uint4*)(sct + base)     = make_uint4(u[0],u[1],u[2],u[3]);
  *(uint4*)(sct + base + 8) = make_uint4(u[4],u[5],u[6],u[7]);
}

// ---------------- fused conv51+conv52 (MFMA) + BN/ReLU + sum + 1x1 conv8 + ReLU ----------------
__global__ __launch_bounds__(256) void k_final_mfma(float* __restrict__ ws, float* __restrict__ out){
  int y = blockIdx.x, b = blockIdx.y;          // (64, 4)
  __shared__ unsigned short Bs[2*3*66*40];     // [conv][dy][pix66][k32 pad40]
  __shared__ float ep[2][2][2][16];            // [wavepair][pt][o][pix16]
  int tid = threadIdx.x;
  int w = tid >> 6, l = tid & 63;
  int g = l >> 4, col = l & 15;
  const unsigned short* sat = (const unsigned short*)(ws + O_SAT);
  const unsigned short* sct = (const unsigned short*)(ws + O_SCT);
  for (int i = tid; i < 1584; i += 256){
    int row = i >> 2, part = i & 3;
    int conv = row / 198; int rr = row - conv*198;
    int dy = rr / 66; int pix = rr - dy*66;
    const unsigned short* src = (conv ? sct : sat) + ((size_t)((b*66 + y + dy)*66 + pix))*32 + part*8;
    *(uint4*)&Bs[(size_t)row*40 + part*8] = *(const uint4*)src;
  }
  int cohalf = w & 1, ptbase = (w >> 1) * 2;
  const unsigned short* wp[2] = { (const unsigned short*)(ws + O_W51P), (const unsigned short*)(ws + O_W52P) };
  bf16x8 wreg[2][9];
  #pragma unroll
  for (int conv = 0; conv < 2; ++conv)
    #pragma unroll
    for (int tap = 0; tap < 9; ++tap)
      wreg[conv][tap] = *(const bf16x8*)(wp[conv] + tap*1024 + (cohalf*16 + col)*32 + g*8);
  __syncthreads();
  f32x4 zero = {0.f,0.f,0.f,0.f};
  f32x4 acc[2][2] = {{zero,zero},{zero,zero}};
  #pragma unroll
  for (int dy = 0; dy < 3; ++dy){
    #pragma unroll
    for (int dx = 0; dx < 3; ++dx){
      int tap = dy*3 + dx;
      #pragma unroll
      for (int conv = 0; conv < 2; ++conv){
        #pragma unroll
        for (int pt = 0; pt < 2; ++pt){
          int pix = (ptbase + pt)*16 + col + dx;
          bf16x8 bv = *(const bf16x8*)&Bs[(size_t)((conv*3 + dy)*66 + pix)*40 + g*8];
          acc[conv][pt] = __builtin_amdgcn_mfma_f32_16x16x32_bf16(wreg[conv][tap], bv, acc[conv][pt], 0, 0, 0);
        }
      }
    }
  }
  float p0[2], p1[2];
  #pragma unroll
  for (int pt = 0; pt < 2; ++pt){
    float s0 = 0.f, s1 = 0.f;
    #pragma unroll
    for (int r = 0; r < 4; ++r){
      int co = cohalf*16 + g*4 + r;
      float A1 = ws[O_BNA + 2*64 + co], B1 = ws[O_BNA + 2*64 + 32 + co];
      float A2 = ws[O_BNA + 3*64 + co], B2 = ws[O_BNA + 3*64 + 32 + co];
      float fs = fmaxf(A1*acc[0][pt][r] + B1, 0.f) + fmaxf(A2*acc[1][pt][r] + B2, 0.f);
      s0 += ws[O_W8 + co]*fs;
      s1 += ws[O_W8 + 32 + co]*fs;
    }
    s0 += __shfl_xor(s0, 16); s0 += __shfl_xor(s0, 32);
    s1 += __shfl_xor(s1, 16); s1 += __shfl_xor(s1, 32);
    p0[pt] = s0; p1[pt] = s1;
  }
  if (cohalf == 0 && l < 16){
    #pragma unroll
    for (int pt = 0; pt < 2; ++pt){ ep[w>>1][pt][0][l] = p0[pt]; ep[w>>1][pt][1][l] = p1[pt]; }
  }
  __syncthreads();
  if (cohalf == 1 && l < 16){
    float b80 = ws[O_W8 + 64], b81 = ws[O_W8 + 65];
    #pragma unroll
    for (int pt = 0; pt < 2; ++pt){
      int pix = y*64 + (w>>1)*32 + pt*16 + l;
      float o0 = p0[pt] + ep[w>>1][pt][0][l] + b80;
      float o1 = p1[pt] + ep[w>>1][pt][1][l] + b81;
      out[((b*2+0)<<12) + pix] = fmaxf(o0, 0.f);
      out[((b*2+1)<<12) + pix] = fmaxf(o1, 0.f);
    }
  }
}

extern "C" void kernel_launch(void* const* d_in, const int* in_sizes, int n_in,
                              void* d_out, int out_size, void* d_ws, size_t ws_size,
                              hipStream_t stream) {
  const float* x    = (const float*)d_in[0];
  float* ws = (float*)d_ws;
  float* out = (float*)d_out;

  k_prep_nhwc<<<3572, 256, 0, stream>>>(
      x,
      (const float*)d_in[1], (const float*)d_in[18],
      (const float*)d_in[13], (const float*)d_in[24],
      (const float*)d_in[2],(const float*)d_in[3],(const float*)d_in[4],(const float*)d_in[5],
      (const float*)d_in[19],(const float*)d_in[20],(const float*)d_in[21],(const float*)d_in[22],
      (const float*)d_in[14],(const float*)d_in[15],(const float*)d_in[16],(const float*)d_in[17],
      (const float*)d_in[25],(const float*)d_in[26],(const float*)d_in[27],(const float*)d_in[28],
      (const float*)d_in[29],(const float*)d_in[30],
      (const float*)d_in[6],(const float*)d_in[7],(const float*)d_in[8],(const float*)d_in[9],
      (const float*)d_in[10],(const float*)d_in[11],(const float*)d_in[12],(const float*)d_in[23],
      ws);
  // R13 instrumentation: conv launched 3x (idempotent). (dur_us - 91.6)/2 = conv time.
  k_conv_mfma<<<1024, 256, 0, stream>>>(ws);
  k_conv_mfma<<<1024, 256, 0, stream>>>(ws);
  k_conv_mfma<<<1024, 256, 0, stream>>>(ws);
  k_feat<<<512, 256, 0, stream>>>(ws);
  k_pam_flash<<<2048, 256, 0, stream>>>(ws);
  k_finred<<<528, 256, 0, stream>>>(ws);
  k_cam_out<<<128, 256, 0, stream>>>(ws);
  k_final_mfma<<<dim3(64,4), 256, 0, stream>>>(ws, out);
}

// Round 14
// 85.258 us; speedup vs baseline: 1.4391x; 1.4391x over previous
//
#include <hip/hip_runtime.h>
#include <hip/hip_bf16.h>

// all I/O is float32 (reference is pure jnp.float32)

typedef __attribute__((ext_vector_type(8))) short bf16x8;
typedef __attribute__((ext_vector_type(4))) float f32x4;

#define AS1 __attribute__((address_space(1)))
#define AS3 __attribute__((address_space(3)))

// ---- ws layout (f32 element offsets) ----
#define O_WPK   0          // Wpack [tap9][cb16][co64][cin32] bf16 (big convs)
#define O_W51P  147456     // [tap9][co32][ci32] bf16
#define O_W52P  152064
#define O_BNA   156672     // [conv{5a,5c,51,52}][{A,B}][32]
#define O_W8    156928     // w8[2][32], b8 at +64
#define O_PQW   157000     // [4][32], bias at +128
#define O_PKW   157132
#define O_PVW   157264     // [32][32], bias at +1024
#define O_GAM   158320     // p_gamma, c_gamma
#define O_Q     158400     // [b4][cr4][4096] f32
#define O_K     223936     // [b4][cr4][4096] f32
#define O_ENE   453312     // [4][32][32]
#define O_F1T   985792     // [b][4096][32] f32 NHWC
#define O_F2T   1510080    // [b][4096][32] f32 NHWC
#define O_V     2034368    // [b][32][4096] bf16
// conv-phase overlay (Xt dead after k_conv_mfma). XT is GRANULE-SWIZZLED:
// logical granule (px, q) of a row lives at byte px*64 + (q ^ ((px>>1)&3))*16.
#define O_XT    461504     // Xt[b4][cb16][66][66][32] bf16 (ends 4922048)
#define O_CP    4922048    // conv partials f32 [ks4][b4][4096pix][64co] (ends 9116352)
// PAM-phase overlays (CP dead after k_feat):
#define O_PO    4922048    // PAM partial O [ms4][b4][n4096][c32] f32 (= old CP)
#define O_PS    3116224    // PAM partial S [ms4][b4][n4096] f32 (inside dead XT)
#define O_PE2   9437184    // CAM energy partials [b4][ch128][32][32] f32 (ends 9961472)
// SAT/SCT OUT of the XT overlay: halo zeroing happens in prep.
#define O_SAT   9961472    // [b][66][66][32] bf16 padded (ends 10240256)
#define O_SCT   10240256   // (ends 10519040; ws ~268MB)

__device__ __forceinline__ unsigned short f2b(float f){
  __hip_bfloat16 h = __float2bfloat16(f);
  return *(unsigned short*)&h;
}

// ---------------- fused: NHWC transform + prep (wpack/misc/XT border/SA-SC halo) ----------------
__global__ __launch_bounds__(256) void k_prep_nhwc(
  const float* __restrict__ x,
  const float* w5a, const float* w5c,
  const float* w51, const float* w52,
  const float* s0,const float* b0,const float* m0,const float* v0,
  const float* s1,const float* b1,const float* m1,const float* v1,
  const float* s2,const float* b2,const float* m2,const float* v2,
  const float* s3,const float* b3,const float* m3,const float* v3,
  const float* w8,const float* b8,
  const float* pqw,const float* pqb,const float* pkw,const float* pkb,
  const float* pvw,const float* pvb,const float* pg,const float* cg,
  float* ws)
{
  int bx = blockIdx.x;
  int tid = threadIdx.x;
  __shared__ unsigned short t16[64][65];
  if (bx < 2048){
    // ---- NHWC+pad bf16 transform -> swizzled Xt[b][cb16][66][66][32]
    int y = bx & 63, ct = (bx >> 6) & 7, b = bx >> 9;
    int r0 = tid >> 4, c0 = (tid & 15) * 4;
    const float* xb = x + ((size_t)(b*512 + ct*64))*4096 + y*64;
    #pragma unroll
    for (int i = 0; i < 4; ++i){
      int row = r0 + i*16;
      float4 v = *(const float4*)(xb + (size_t)row*4096 + c0);
      t16[row][c0+0] = f2b(v.x);
      t16[row][c0+1] = f2b(v.y);
      t16[row][c0+2] = f2b(v.z);
      t16[row][c0+3] = f2b(v.w);
    }
    __syncthreads();
    int pixl = tid >> 2, q = tid & 3;
    unsigned short vs[16];
    #pragma unroll
    for (int j = 0; j < 16; ++j) vs[j] = t16[q*16 + j][pixl];
    unsigned u[8];
    #pragma unroll
    for (int j = 0; j < 8; ++j) u[j] = (unsigned)vs[2*j] | ((unsigned)vs[2*j+1] << 16);
    unsigned short* xt = (unsigned short*)(ws + O_XT);
    int cbl = ct*2 + (q>>1);
    int pxe = pixl + 1;
    int sw = (pxe >> 1) & 3;                 // granule swizzle for this pixel
    int g0 = (2*(q&1)) ^ sw;                 // logical granules 2(q&1), 2(q&1)+1
    int g1 = g0 ^ 1;
    size_t base = (((size_t)(b*16 + cbl)*66 + (y+1))*66 + pxe)*32;
    *(uint4*)(xt + base + g0*8) = make_uint4(u[0],u[1],u[2],u[3]);
    *(uint4*)(xt + base + g1*8) = make_uint4(u[4],u[5],u[6],u[7]);
    return;
  }
  int pbx = bx - 2048;
  if (pbx < 1152){
    int id = pbx*256 + tid;   // 294912
    int tap = id >> 15;
    int r = id & 32767;
    int cb = r >> 11;
    int r2 = r & 2047;
    int co = r2 >> 5, ci = r2 & 31;
    int cin = cb*32 + ci;
    float v = (co < 32) ? w5a[co*4608 + cin*9 + tap] : w5c[(co-32)*4608 + cin*9 + tap];
    ((unsigned short*)ws)[id] = f2b(v);
    return;
  }
  if (pbx < 1231){
    int id = (pbx-1152)*256 + tid;
    if (id >= 20076) return;
    if (id < 9216){ int tap=id>>10, co=(id>>5)&31, ci=id&31;
      ((unsigned short*)(ws + O_W51P))[id] = f2b(w51[co*288 + ci*9 + tap]); return; }
    id -= 9216;
    if (id < 9216){ int tap=id>>10, co=(id>>5)&31, ci=id&31;
      ((unsigned short*)(ws + O_W52P))[id] = f2b(w52[co*288 + ci*9 + tap]); return; }
    id -= 9216;
    if (id < 256){
      int conv = id>>6, ab = (id>>5)&1, c = id&31;
      const float *S,*Bb,*M,*V;
      if (conv==0){S=s0;Bb=b0;M=m0;V=v0;} else if (conv==1){S=s1;Bb=b1;M=m1;V=v1;}
      else if (conv==2){S=s2;Bb=b2;M=m2;V=v2;} else {S=s3;Bb=b3;M=m3;V=v3;}
      float A = S[c] * rsqrtf(V[c] + 1e-5f);
      ws[O_BNA + conv*64 + ab*32 + c] = ab ? (Bb[c] - M[c]*A) : A;
      return; }
    id -= 256;
    if (id < 64){ ws[O_W8+id] = w8[id]; return; } id -= 64;
    if (id < 2){ ws[O_W8+64+id] = b8[id]; return; } id -= 2;
    if (id < 128){ ws[O_PQW+id] = pqw[id]; return; } id -= 128;
    if (id < 4){ ws[O_PQW+128+id] = pqb[id]; return; } id -= 4;
    if (id < 128){ ws[O_PKW+id] = pkw[id]; return; } id -= 128;
    if (id < 4){ ws[O_PKW+128+id] = pkb[id]; return; } id -= 4;
    if (id < 1024){ ws[O_PVW+id] = pvw[id]; return; } id -= 1024;
    if (id < 32){ ws[O_PVW+1024+id] = pvb[id]; return; } id -= 32;
    ws[O_GAM+id] = id ? cg[0] : pg[0];
    return;
  }
  if (pbx < 1491){
    // ---- zero Xt borders: whole 64B pixels zeroed -> granule swizzle irrelevant
    int i = (pbx-1231)*256 + tid;   // 66560 uint4
    if (i >= 66560) return;
    int part = i & 3; int j = i >> 2;
    int rp = j % 260; int bc = j / 260;
    int py, px;
    if (rp < 66){ py = 0; px = rp; }
    else if (rp < 132){ py = 65; px = rp - 66; }
    else if (rp < 196){ py = rp - 131; px = 0; }
    else { py = rp - 195; px = 65; }
    size_t off = (((size_t)bc*66 + py)*66 + px)*32 + part*8;
    *(uint4*)((unsigned short*)(ws + O_XT) + off) = make_uint4(0,0,0,0);
    return;
  }
  {
    // ---- zero SA_t / SC_t borders (SAT/SCT do not alias XT — safe here)
    int i = (pbx-1491)*256 + tid;   // 8320 uint4
    if (i >= 8320) return;
    int part = i & 3; int j = i >> 2;
    int arr = j / 1040; int rem = j - arr*1040;
    int b = rem / 260; int rp = rem % 260;
    int py, px;
    if (rp < 66){ py = 0; px = rp; }
    else if (rp < 132){ py = 65; px = rp - 66; }
    else if (rp < 196){ py = rp - 131; px = 0; }
    else { py = rp - 195; px = 65; }
    size_t off = (((size_t)(b*66) + py)*66 + px)*32 + part*8;
    unsigned short* base = (unsigned short*)(ws + (arr ? O_SCT : O_SAT));
    *(uint4*)(base + off) = make_uint4(0,0,0,0);
  }
}

// ---------------- big convs as implicit GEMM via MFMA (glds dbuf + weight reg-prefetch) ----------------
__global__ __launch_bounds__(256, 4) void k_conv_mfma(float* __restrict__ ws){
  int bx = blockIdx.x;          // 1024 flat
  int xcd = bx & 7, kk2 = bx >> 3;
  int pairIdx = ((kk2 >> 6) << 3) + xcd;   // 0..15
  int b = pairIdx >> 2, ks = pairIdx & 3;
  int y = kk2 & 63;
  __shared__ __align__(16) unsigned short Bs[2][6336];   // [buf][(dy*66+px)*32 + swz-granule]
  int tid = threadIdx.x;
  int w = tid >> 6, l = tid & 63;
  int bl = l & 15, qh = l >> 4;
  f32x4 zero = {0.f,0.f,0.f,0.f};
  f32x4 acc[4] = {zero, zero, zero, zero};
  const unsigned short* wp = (const unsigned short*)ws;
  const unsigned short* xt = (const unsigned short*)(ws + O_XT);
  int arow = w*16 + bl;
  int kq = qh*8;
  // swizzled read offsets: (px)*32 + (qh ^ ((px>>1)&3))*8 for px = bl+dx
  int qx0 = ((qh ^ ((bl>>1)&3)) << 3) + bl*32;
  int qx1 = ((qh ^ (((bl+1)>>1)&3)) << 3) + (bl+1)*32;
  int qx2 = ((qh ^ (((bl+2)>>1)&3)) << 3) + (bl+2)*32;
  bf16x8 afA[9], afB[9];

#define CF_STAGE(BUF, CB) { \
    const unsigned short* slab = xt + (size_t)((b*16 + (CB))*66 + y)*2112; \
    _Pragma("unroll") \
    for (int cc = 0; cc < 3; ++cc){ \
      int kk = w*3 + cc; \
      __builtin_amdgcn_global_load_lds((const AS1 unsigned int*)(slab + kk*512 + l*8), \
                                       (AS3 unsigned int*)(&Bs[BUF][kk*512]), 16, 0, 0); \
    } \
    if (w == 3 && l < 24) \
      __builtin_amdgcn_global_load_lds((const AS1 unsigned int*)(slab + 6144 + l*8), \
                                       (AS3 unsigned int*)(&Bs[BUF][6144]), 16, 0, 0); \
  }

#define CF_LOAD_AF(DST, CB) { \
    _Pragma("unroll") \
    for (int t = 0; t < 9; ++t) \
      DST[t] = *(const bf16x8*)(wp + (size_t)(t*16 + (CB))*2048 + arow*32 + kq); \
  }

#define CF_COMPUTE(BUF, AF) { \
    _Pragma("unroll") \
    for (int tap = 0; tap < 9; ++tap){ \
      int dy = tap/3, dx = tap - dy*3; \
      int qx = (dx==0) ? qx0 : (dx==1) ? qx1 : qx2; \
      _Pragma("unroll") \
      for (int pt = 0; pt < 4; ++pt){ \
        bf16x8 bv = *(const bf16x8*)&Bs[BUF][dy*2112 + pt*512 + qx]; \
        acc[pt] = __builtin_amdgcn_mfma_f32_16x16x32_bf16(AF[tap], bv, acc[pt], 0, 0, 0); \
      } \
    } }

  int cb0 = ks*4;
  CF_STAGE(0, cb0)
  CF_LOAD_AF(afA, cb0)
  __syncthreads();
  CF_STAGE(1, cb0+1)
  CF_LOAD_AF(afB, cb0+1)
  CF_COMPUTE(0, afA)
  __syncthreads();
  CF_STAGE(0, cb0+2)
  CF_LOAD_AF(afA, cb0+2)
  CF_COMPUTE(1, afB)
  __syncthreads();
  CF_STAGE(1, cb0+3)
  CF_LOAD_AF(afB, cb0+3)
  CF_COMPUTE(0, afA)
  __syncthreads();
  CF_COMPUTE(1, afB)
#undef CF_STAGE
#undef CF_LOAD_AF
#undef CF_COMPUTE

  float* cp = ws + O_CP + ((size_t)(ks*4 + b))*262144;
  int co0 = w*16 + qh*4;
  #pragma unroll
  for (int pt = 0; pt < 4; ++pt){
    int pix = y*64 + pt*16 + bl;
    *(f32x4*)&cp[(size_t)pix*64 + co0] = acc[pt];
  }
}

// ---------------- fused: CP reduce + BN/ReLU -> F1T/F2T (+LDS) + qkv + CAM partials ----------------
__global__ __launch_bounds__(256) void k_feat(float* __restrict__ ws){
  int bx = blockIdx.x;   // 512
  int tid = threadIdx.x;
  __shared__ float Fl[32][68];               // [pix][co64 +pad]
  __shared__ float wqs[4][32], wks[4][32], wvs[32][32];
  int b = bx >> 7, chunk = bx & 127;         // 128 chunks of 32 pix
  for (int i = tid; i < 1280; i += 256){
    if (i < 128)      ((float*)wqs)[i]     = ws[O_PQW + i];
    else if (i < 256) ((float*)wks)[i-128] = ws[O_PKW + (i-128)];
    else              ((float*)wvs)[i-256] = ws[O_PVW + (i-256)];
  }
  int pix = tid >> 3, cg = tid & 7;          // 8 co per thread
  int pixg = (chunk << 5) + pix;
  const float* cpb = ws + O_CP + (size_t)b*262144 + (size_t)pixg*64 + cg*8;
  f32x4 sa_ = *(const f32x4*)(cpb);
  f32x4 sb_ = *(const f32x4*)(cpb + 4);
  {
    f32x4 t0 = *(const f32x4*)(cpb + 1048576);
    f32x4 t1 = *(const f32x4*)(cpb + 1048576 + 4);
    f32x4 t2 = *(const f32x4*)(cpb + 2097152);
    f32x4 t3 = *(const f32x4*)(cpb + 2097152 + 4);
    f32x4 t4 = *(const f32x4*)(cpb + 3145728);
    f32x4 t5 = *(const f32x4*)(cpb + 3145728 + 4);
    sa_ = (sa_ + t0) + (t2 + t4);
    sb_ = (sb_ + t1) + (t3 + t5);
  }
  int co0 = cg*8;
  int conv = co0 >> 5, cc0 = co0 & 31;       // 8-group never straddles conv boundary
  float v8[8];
  #pragma unroll
  for (int j = 0; j < 8; ++j){
    int c = cc0 + j;
    float A = ws[O_BNA + conv*64 + c], Bb = ws[O_BNA + conv*64 + 32 + c];
    float s = (j < 4) ? sa_[j] : sb_[j-4];
    v8[j] = fmaxf(A*s + Bb, 0.f);
  }
  float* fdst = ws + (conv == 0 ? O_F1T : O_F2T) + ((size_t)(b*4096 + pixg))*32 + cc0;
  *(f32x4*)(fdst)     = (f32x4){v8[0],v8[1],v8[2],v8[3]};
  *(f32x4*)(fdst + 4) = (f32x4){v8[4],v8[5],v8[6],v8[7]};
  *(f32x4*)&Fl[pix][co0]     = (f32x4){v8[0],v8[1],v8[2],v8[3]};
  *(f32x4*)&Fl[pix][co0 + 4] = (f32x4){v8[4],v8[5],v8[6],v8[7]};
  __syncthreads();
  // ---- qkv phase (threads 0..127): part, pixel
  if (tid < 128){
    int part = tid >> 5, pixl = tid & 31;
    int n = (chunk << 5) + pixl;
    float fv[32];
    #pragma unroll
    for (int c = 0; c < 32; ++c) fv[c] = Fl[pixl][c];
    float q = ws[O_PQW+128+part], k = ws[O_PKW+128+part];
    #pragma unroll
    for (int c = 0; c < 32; ++c){ q += wqs[part][c]*fv[c]; k += wks[part][c]*fv[c]; }
    ws[O_Q + (((b<<2)+part)<<12) + n] = q;
    ws[O_K + (((b<<2)+part)<<12) + n] = k;
    unsigned short* vbp = (unsigned short*)(ws + O_V);
    #pragma unroll
    for (int j2 = 0; j2 < 8; ++j2){
      int c2 = part*8 + j2;
      float v = ws[O_PVW+1024+c2];
      #pragma unroll
      for (int c = 0; c < 32; ++c) v += wvs[c2][c]*fv[c];
      vbp[(((b<<5)+c2)<<12) + n] = f2b(v);
    }
  }
  // ---- CAM energy partial (all 256 threads), F2 = Fl[:,32..63]
  {
    int ce = tid >> 3, d0 = (tid & 7) * 4;
    float a0=0.f, a1=0.f, a2=0.f, a3=0.f;
    #pragma unroll 8
    for (int n = 0; n < 32; ++n){
      float fc = Fl[n][32 + ce];
      float f0 = Fl[n][32 + d0], f1 = Fl[n][32 + d0 + 1];
      float f2 = Fl[n][32 + d0 + 2], f3 = Fl[n][32 + d0 + 3];
      a0 = fmaf(fc, f0, a0); a1 = fmaf(fc, f1, a1);
      a2 = fmaf(fc, f2, a2); a3 = fmaf(fc, f3, a3);
    }
    float* pe = ws + O_PE2 + ((size_t)(b*128 + chunk))*1024 + ce*32 + d0;
    *(f32x4*)pe = (f32x4){a0, a1, a2, a3};
  }
}

// ---------------- PAM flash (+ CAM ENE reduce as extra blocks) ----------------
// XCD-swizzled flat grid (2048): all 128 nt-blocks of one (b,ms) pair land on ONE XCD.
// bx >= 2048: ENE[b][c][d] = sum over 128 PE2 chunk partials (PE2 ready: feat precedes).
__global__ __launch_bounds__(256, 6) void k_pam_flash(float* __restrict__ ws){
  int bx = blockIdx.x;
  int tid = threadIdx.x;
  if (bx >= 2048){
    int id = (bx-2048)*256 + tid;   // 4096 = b*1024 + i
    int b = id >> 10, i = id & 1023;
    const float* pe = ws + O_PE2 + ((size_t)b)*131072 + i;
    float s = 0.f;
    #pragma unroll 8
    for (int chk = 0; chk < 128; ++chk) s += pe[chk*1024];
    ws[O_ENE + id] = s;
    return;
  }
  int xcd = bx & 7, kf = bx >> 3;       // kf 0..255
  int pair = ((kf >> 7) << 3) + xcd;    // 0..15
  int b  = pair >> 2;
  int ms = pair & 3;
  int nt = kf & 127;                    // 0..127 n-tile of 32
  __shared__ float Ks[2][4][4][32];    // [buf][wave][cr][m32]  4 KB
  __shared__ float Ss[4][32];
  __shared__ float Os[4][32][36];      // 18 KB
  int w = tid >> 6, l = tid & 63;
  int nn = l & 15, g = l >> 4;
  int n0 = (nt<<5) + nn;
  const float LOG2E = 1.44269504f;
  const float BIAS  = -28.8539008f;   // -20*log2(e); fixed shift, energies O(+-35)
  float q0[4], q1[4];
  #pragma unroll
  for (int cr=0;cr<4;++cr){
    q0[cr] = ws[O_Q + (((b<<2)+cr)<<12) + n0] * LOG2E;
    q1[cr] = ws[O_Q + (((b<<2)+cr)<<12) + n0 + 16] * LOG2E;
  }
  int e0i = l*2, cr_s = e0i >> 5, mm_s = e0i & 31;
  int mbase = ms*1024 + w*256;        // wave owns m in [mbase, mbase+256), 8 chunks
  const float* ksrc = ws + O_K + (((b<<2)+cr_s)<<12) + mbase + mm_s;
  const unsigned short* vb = (const unsigned short*)(ws + O_V);
  int mo = g*8;
  const unsigned short* vp0 = vb + (((b<<5) + nn)<<12) + mbase + mo;
  const unsigned short* vp1 = vb + (((b<<5) + 16 + nn)<<12) + mbase + mo;
  f32x4 zero = {0.f,0.f,0.f,0.f};
  f32x4 acc00 = zero, acc01 = zero, acc10 = zero, acc11 = zero;
  float lsum0 = 0.f, lsum1 = 0.f;
  bf16x8 a0A = *(const bf16x8*)(vp0);
  bf16x8 a1A = *(const bf16x8*)(vp1);
  float2 kreg = *(const float2*)(ksrc);
  *(float2*)&Ks[0][w][cr_s][mm_s] = kreg;
  bf16x8 a0B, a1B;
  for (int ch = 0; ch < 8; ++ch){
    int buf = ch & 1;
    if (ch < 7){
      int mn = (ch+1)*32;
      a0B = *(const bf16x8*)(vp0 + mn);
      a1B = *(const bf16x8*)(vp1 + mn);
      kreg = *(const float2*)(ksrc + mn);
    }
    float e0[8], e1[8];
    {
      float4 ka, kb;
      ka = *(const float4*)&Ks[buf][w][0][mo];
      kb = *(const float4*)&Ks[buf][w][0][mo+4];
      e0[0]=fmaf(q0[0],ka.x,BIAS); e0[1]=fmaf(q0[0],ka.y,BIAS); e0[2]=fmaf(q0[0],ka.z,BIAS); e0[3]=fmaf(q0[0],ka.w,BIAS);
      e0[4]=fmaf(q0[0],kb.x,BIAS); e0[5]=fmaf(q0[0],kb.y,BIAS); e0[6]=fmaf(q0[0],kb.z,BIAS); e0[7]=fmaf(q0[0],kb.w,BIAS);
      e1[0]=fmaf(q1[0],ka.x,BIAS); e1[1]=fmaf(q1[0],ka.y,BIAS); e1[2]=fmaf(q1[0],ka.z,BIAS); e1[3]=fmaf(q1[0],ka.w,BIAS);
      e1[4]=fmaf(q1[0],kb.x,BIAS); e1[5]=fmaf(q1[0],kb.y,BIAS); e1[6]=fmaf(q1[0],kb.z,BIAS); e1[7]=fmaf(q1[0],kb.w,BIAS);
#define KACC(CR) \
      ka = *(const float4*)&Ks[buf][w][CR][mo]; \
      kb = *(const float4*)&Ks[buf][w][CR][mo+4]; \
      e0[0]=fmaf(q0[CR],ka.x,e0[0]); e0[1]=fmaf(q0[CR],ka.y,e0[1]); e0[2]=fmaf(q0[CR],ka.z,e0[2]); e0[3]=fmaf(q0[CR],ka.w,e0[3]); \
      e0[4]=fmaf(q0[CR],kb.x,e0[4]); e0[5]=fmaf(q0[CR],kb.y,e0[5]); e0[6]=fmaf(q0[CR],kb.z,e0[6]); e0[7]=fmaf(q0[CR],kb.w,e0[7]); \
      e1[0]=fmaf(q1[CR],ka.x,e1[0]); e1[1]=fmaf(q1[CR],ka.y,e1[1]); e1[2]=fmaf(q1[CR],ka.z,e1[2]); e1[3]=fmaf(q1[CR],ka.w,e1[3]); \
      e1[4]=fmaf(q1[CR],kb.x,e1[4]); e1[5]=fmaf(q1[CR],kb.y,e1[5]); e1[6]=fmaf(q1[CR],kb.z,e1[6]); e1[7]=fmaf(q1[CR],kb.w,e1[7]);
      KACC(1)
      KACC(2)
      KACC(3)
#undef KACC
    }
    union { bf16x8 v; unsigned short u[8]; } pb0, pb1;
    #pragma unroll
    for (int j=0;j<8;j++){ float p = __builtin_amdgcn_exp2f(e0[j]); lsum0 += p; pb0.u[j] = f2b(p); }
    #pragma unroll
    for (int j=0;j<8;j++){ float p = __builtin_amdgcn_exp2f(e1[j]); lsum1 += p; pb1.u[j] = f2b(p); }
    acc00 = __builtin_amdgcn_mfma_f32_16x16x32_bf16(a0A, pb0.v, acc00, 0, 0, 0);
    acc01 = __builtin_amdgcn_mfma_f32_16x16x32_bf16(a1A, pb0.v, acc01, 0, 0, 0);
    acc10 = __builtin_amdgcn_mfma_f32_16x16x32_bf16(a0A, pb1.v, acc10, 0, 0, 0);
    acc11 = __builtin_amdgcn_mfma_f32_16x16x32_bf16(a1A, pb1.v, acc11, 0, 0, 0);
    if (ch < 7){
      int nb = buf ^ 1;
      *(float2*)&Ks[nb][w][cr_s][mm_s] = kreg;
      a0A = a0B; a1A = a1B;
    }
  }
  lsum0 += __shfl_xor(lsum0, 16); lsum0 += __shfl_xor(lsum0, 32);
  lsum1 += __shfl_xor(lsum1, 16); lsum1 += __shfl_xor(lsum1, 32);
  if (l < 16){ Ss[w][l] = lsum0; Ss[w][16+l] = lsum1; }
  #pragma unroll
  for (int r=0;r<4;r++){
    Os[w][nn][g*4 + r]         = acc00[r];
    Os[w][nn][16 + g*4 + r]    = acc01[r];
    Os[w][16+nn][g*4 + r]      = acc10[r];
    Os[w][16+nn][16 + g*4 + r] = acc11[r];
  }
  __syncthreads();
  float* PO = ws + O_PO + (size_t)(ms*4+b)*131072 + nt*1024;
  for (int i = tid; i < 1024; i += 256){
    int nn2 = i >> 5, c = i & 31;
    PO[i] = Os[0][nn2][c] + Os[1][nn2][c] + Os[2][nn2][c] + Os[3][nn2][c];
  }
  if (tid < 32)
    ws[O_PS + (ms*4+b)*4096 + (nt<<5) + tid] = Ss[0][tid]+Ss[1][tid]+Ss[2][tid]+Ss[3][tid];
}

// ---------------- fused: PAM finalize (vectorized) + CAM att + out -> SC_t ----------------
// ENE is ready (computed in k_pam_flash's extra blocks), so cam_out merges here:
// bx < 512 = PAM finalize; bx >= 512 = CAM attention + output (128 blocks).
__global__ __launch_bounds__(256) void k_finred(float* __restrict__ ws){
  int bx = blockIdx.x;
  int tid = threadIdx.x;
  __shared__ float att[32][33];
  if (bx < 512){
    int id = bx*256 + tid;   // 131072 = (b, n, c-quad)
    int cq = (id & 7) * 4;
    int n  = (id >> 3) & 4095;
    int b  = id >> 15;
    size_t pbase = (size_t)(b*4096 + n)*32 + cq;
    int sbase = b*4096 + n;
    f32x4 O = *(const f32x4*)(ws + O_PO + pbase);
    O = O + *(const f32x4*)(ws + O_PO + 524288 + pbase);
    O = O + *(const f32x4*)(ws + O_PO + 1048576 + pbase);
    O = O + *(const f32x4*)(ws + O_PO + 1572864 + pbase);
    float S = ws[O_PS + sbase] + ws[O_PS + 16384 + sbase]
            + ws[O_PS + 32768 + sbase] + ws[O_PS + 49152 + sbase];
    float gam = ws[O_GAM];
    f32x4 f1 = *(const f32x4*)(ws + O_F1T + (size_t)id*4);
    unsigned short h[4];
    #pragma unroll
    for (int j = 0; j < 4; ++j) h[j] = f2b(gam*(O[j]/S) + f1[j]);
    int y = n >> 6, xx = n & 63;
    unsigned short* sat = (unsigned short*)(ws + O_SAT);
    uint2 u; u.x = (unsigned)h[0] | ((unsigned)h[1] << 16);
             u.y = (unsigned)h[2] | ((unsigned)h[3] << 16);
    *(uint2*)&sat[(((size_t)((b*66 + y+1)*66 + xx+1))<<5) + cq] = u;
    return;
  }
  {
    int blk = bx - 512;              // 128
    int b = blk >> 5;
    int chunk = blk & 31;
    int half = tid >> 7;             // 0/1
    int nl = tid & 127;
    int n = (chunk << 7) + nl;
    if (tid < 32){
      int c = tid;
      const float* e = ws + O_ENE + (b<<10) + (c<<5);
      float M = -1e30f, mn = 1e30f;
      #pragma unroll
      for (int d=0;d<32;d++){ M = fmaxf(M, e[d]); mn = fminf(mn, e[d]); }
      float mx2 = M - mn;
      float s = 0.f, ex[32];
      #pragma unroll
      for (int d=0;d<32;d++){ ex[d] = __expf((M - e[d]) - mx2); s += ex[d]; }
      float inv = 1.f/s;
      #pragma unroll
      for (int d=0;d<32;d++) att[c][d] = ex[d]*inv;
    }
    __syncthreads();
    const float* fp = ws + O_F2T + (((size_t)b<<12) + n)*32;
    float fv[32];
    #pragma unroll
    for (int j=0;j<8;j++){
      float4 v = *(const float4*)(fp + j*4);
      fv[j*4]=v.x; fv[j*4+1]=v.y; fv[j*4+2]=v.z; fv[j*4+3]=v.w;
    }
    float g = ws[O_GAM+1];
    int c0 = half*16;
    unsigned u[8];
    #pragma unroll
    for (int cp=0; cp<8; ++cp){
      int ca = c0 + 2*cp, cb = ca + 1;
      float o0 = 0.f, o1 = 0.f;
      #pragma unroll
      for (int d=0;d<32;d++){ o0 += att[ca][d]*fv[d]; o1 += att[cb][d]*fv[d]; }
      float r0 = g*o0 + fv[ca], r1 = g*o1 + fv[cb];
      u[cp] = (unsigned)f2b(r0) | ((unsigned)f2b(r1) << 16);
    }
    int y = n >> 6, xcol = n & 63;
    unsigned short* sct = (unsigned short*)(ws + O_SCT);
    size_t base = ((size_t)((b*66 + y+1)*66 + xcol+1))*32 + c0;
    *(uint4*)(sct + base)     = make_uint4(u[0],u[1],u[2],u[3]);
    *(uint4*)(sct + base + 8) = make_uint4(u[4],u[5],u[6],u[7]);
  }
}

// ---------------- fused conv51+conv52 (MFMA) + BN/ReLU + sum + 1x1 conv8 + ReLU ----------------
__global__ __launch_bounds__(256) void k_final_mfma(float* __restrict__ ws, float* __restrict__ out){
  int y = blockIdx.x, b = blockIdx.y;          // (64, 4)
  __shared__ unsigned short Bs[2*3*66*40];     // [conv][dy][pix66][k32 pad40]
  __shared__ float ep[2][2][2][16];            // [wavepair][pt][o][pix16]
  int tid = threadIdx.x;
  int w = tid >> 6, l = tid & 63;
  int g = l >> 4, col = l & 15;
  const unsigned short* sat = (const unsigned short*)(ws + O_SAT);
  const unsigned short* sct = (const unsigned short*)(ws + O_SCT);
  for (int i = tid; i < 1584; i += 256){
    int row = i >> 2, part = i & 3;
    int conv = row / 198; int rr = row - conv*198;
    int dy = rr / 66; int pix = rr - dy*66;
    const unsigned short* src = (conv ? sct : sat) + ((size_t)((b*66 + y + dy)*66 + pix))*32 + part*8;
    *(uint4*)&Bs[(size_t)row*40 + part*8] = *(const uint4*)src;
  }
  int cohalf = w & 1, ptbase = (w >> 1) * 2;
  const unsigned short* wp[2] = { (const unsigned short*)(ws + O_W51P), (const unsigned short*)(ws + O_W52P) };
  bf16x8 wreg[2][9];
  #pragma unroll
  for (int conv = 0; conv < 2; ++conv)
    #pragma unroll
    for (int tap = 0; tap < 9; ++tap)
      wreg[conv][tap] = *(const bf16x8*)(wp[conv] + tap*1024 + (cohalf*16 + col)*32 + g*8);
  __syncthreads();
  f32x4 zero = {0.f,0.f,0.f,0.f};
  f32x4 acc[2][2] = {{zero,zero},{zero,zero}};
  #pragma unroll
  for (int dy = 0; dy < 3; ++dy){
    #pragma unroll
    for (int dx = 0; dx < 3; ++dx){
      int tap = dy*3 + dx;
      #pragma unroll
      for (int conv = 0; conv < 2; ++conv){
        #pragma unroll
        for (int pt = 0; pt < 2; ++pt){
          int pix = (ptbase + pt)*16 + col + dx;
          bf16x8 bv = *(const bf16x8*)&Bs[(size_t)((conv*3 + dy)*66 + pix)*40 + g*8];
          acc[conv][pt] = __builtin_amdgcn_mfma_f32_16x16x32_bf16(wreg[conv][tap], bv, acc[conv][pt], 0, 0, 0);
        }
      }
    }
  }
  float p0[2], p1[2];
  #pragma unroll
  for (int pt = 0; pt < 2; ++pt){
    float s0 = 0.f, s1 = 0.f;
    #pragma unroll
    for (int r = 0; r < 4; ++r){
      int co = cohalf*16 + g*4 + r;
      float A1 = ws[O_BNA + 2*64 + co], B1 = ws[O_BNA + 2*64 + 32 + co];
      float A2 = ws[O_BNA + 3*64 + co], B2 = ws[O_BNA + 3*64 + 32 + co];
      float fs = fmaxf(A1*acc[0][pt][r] + B1, 0.f) + fmaxf(A2*acc[1][pt][r] + B2, 0.f);
      s0 += ws[O_W8 + co]*fs;
      s1 += ws[O_W8 + 32 + co]*fs;
    }
    s0 += __shfl_xor(s0, 16); s0 += __shfl_xor(s0, 32);
    s1 += __shfl_xor(s1, 16); s1 += __shfl_xor(s1, 32);
    p0[pt] = s0; p1[pt] = s1;
  }
  if (cohalf == 0 && l < 16){
    #pragma unroll
    for (int pt = 0; pt < 2; ++pt){ ep[w>>1][pt][0][l] = p0[pt]; ep[w>>1][pt][1][l] = p1[pt]; }
  }
  __syncthreads();
  if (cohalf == 1 && l < 16){
    float b80 = ws[O_W8 + 64], b81 = ws[O_W8 + 65];
    #pragma unroll
    for (int pt = 0; pt < 2; ++pt){
      int pix = y*64 + (w>>1)*32 + pt*16 + l;
      float o0 = p0[pt] + ep[w>>1][pt][0][l] + b80;
      float o1 = p1[pt] + ep[w>>1][pt][1][l] + b81;
      out[((b*2+0)<<12) + pix] = fmaxf(o0, 0.f);
      out[((b*2+1)<<12) + pix] = fmaxf(o1, 0.f);
    }
  }
}

extern "C" void kernel_launch(void* const* d_in, const int* in_sizes, int n_in,
                              void* d_out, int out_size, void* d_ws, size_t ws_size,
                              hipStream_t stream) {
  const float* x    = (const float*)d_in[0];
  float* ws = (float*)d_ws;
  float* out = (float*)d_out;

  k_prep_nhwc<<<3572, 256, 0, stream>>>(
      x,
      (const float*)d_in[1], (const float*)d_in[18],
      (const float*)d_in[13], (const float*)d_in[24],
      (const float*)d_in[2],(const float*)d_in[3],(const float*)d_in[4],(const float*)d_in[5],
      (const float*)d_in[19],(const float*)d_in[20],(const float*)d_in[21],(const float*)d_in[22],
      (const float*)d_in[14],(const float*)d_in[15],(const float*)d_in[16],(const float*)d_in[17],
      (const float*)d_in[25],(const float*)d_in[26],(const float*)d_in[27],(const float*)d_in[28],
      (const float*)d_in[29],(const float*)d_in[30],
      (const float*)d_in[6],(const float*)d_in[7],(const float*)d_in[8],(const float*)d_in[9],
      (const float*)d_in[10],(const float*)d_in[11],(const float*)d_in[12],(const float*)d_in[23],
      ws);
  k_conv_mfma<<<1024, 256, 0, stream>>>(ws);
  k_feat<<<512, 256, 0, stream>>>(ws);
  k_pam_flash<<<2064, 256, 0, stream>>>(ws);
  k_finred<<<640, 256, 0, stream>>>(ws);
  k_final_mfma<<<dim3(64,4), 256, 0, stream>>>(ws, out);
}